// Round 11
// baseline (249.522 us; speedup 1.0000x reference)
//
#include <hip/hip_runtime.h>

#define NUM_ITERS 500
#define LR_F 0.001f
#define KRYLOV 3
#define VPLANE 262144    // 4*64*1024 floats per Krylov vector
// 500 = 20 segments * 25 steps; C(25,1)=25, C(25,2)=300, C(25,3)=2300
// Band-conv LDS pitch 48: 48%32=16 -> ldrow8b start bank = c0 + 16*parity(row)
// -> exact 2-way aliasing (free). Pitch 40 (%32=8) was 4-way (8.15M confl cyc).
#define BP 48            // band pitch
#define BPL 288          // band plane (6*48)
#define BDB 1152         // double-buffer offset (4 planes)

// ---- register-safe unpack helpers -------------------------------------------
__device__ __forceinline__ void ldw12(const float* __restrict__ wp, float w[12]) {
  float4 q0 = ((const float4*)wp)[0];
  float4 q1 = ((const float4*)wp)[1];
  float4 q2 = ((const float4*)wp)[2];
  w[0] = q0.x; w[1] = q0.y; w[2] = q0.z; w[3] = q0.w;
  w[4] = q1.x; w[5] = q1.y; w[6] = q1.z; w[7] = q1.w;
  w[8] = q2.x; w[9] = q2.y; w[10] = q2.z; w[11] = q2.w;
}

// aligned b128 pair: f[0..7] = LDS words rp..rp+7 (rp 4-word aligned)
__device__ __forceinline__ void ldrow8b(const float* __restrict__ rp, float f[8]) {
  float4 a = *(const float4*)(rp);
  float4 b = *(const float4*)(rp + 4);
  f[0] = a.x; f[1] = a.y; f[2] = a.z; f[3] = a.w;
  f[4] = b.x; f[5] = b.y; f[6] = b.z; f[7] = b.w;
}

// load 25 (padded 28) weights for row o from table base (stride 32, 16B aligned)
__device__ __forceinline__ void wload(const float* __restrict__ gb, int o, float w[28]) {
  const float4* g4 = (const float4*)(gb + o * 32);
#pragma unroll
  for (int i = 0; i < 7; ++i) {
    float4 v = g4[i];
    w[4 * i] = v.x; w[4 * i + 1] = v.y; w[4 * i + 2] = v.z; w[4 * i + 3] = v.w;
  }
}

// staging write helper: float4 -> LDS word addr == 2 (mod 4), as two float2
__device__ __forceinline__ void stg_write(float* sd, float4 v) {
  float2 u = {v.x, v.y}, w = {v.z, v.w};
  *(float2*)sd = u;
  *(float2*)(sd + 2) = w;
}

// ---- weight prep ------------------------------------------------------------
// table0: WtF2[ciQ(4)][oT(4)][o16(16)][ci32(32)][12]  (forward, transposed)
// table1: WffI[coT(8)][ciH(2)][co16(16)][ci32(32)][12], slot9 = Wb (bypass)
// table2: WFlip[co*64+ci][12] (flipped 3x3)
__global__ __launch_bounds__(256) void k_prep(const float* __restrict__ Wff,
                                              const float* __restrict__ Wfb,
                                              const float* __restrict__ Wb,
                                              float* __restrict__ WffI,
                                              float* __restrict__ WtF,
                                              float* __restrict__ WFlip) {
  int g = blockIdx.x * 256 + threadIdx.x;
  int table = g >> 13, t = g & 8191;
  float w[12];
#pragma unroll
  for (int k = 0; k < 12; ++k) w[k] = 0.f;
  float* dst;
  if (table == 0) {
    int o = t >> 7, c = t & 127;
    const float* src = Wfb + (size_t)(c * 64 + o) * 9;
#pragma unroll
    for (int k = 0; k < 9; ++k) w[k] = src[k];
    int ciQ = c >> 5, ci32 = c & 31, oT = o >> 4, o16 = o & 15;
    dst = WtF + ((size_t)(((ciQ * 4 + oT) * 16 + o16) * 32) + ci32) * 12;
  } else if (table == 1) {
    int co = t >> 6, ci = t & 63;
    const float* src = Wff + (size_t)t * 9;
#pragma unroll
    for (int k = 0; k < 9; ++k) w[k] = src[k];
    w[9] = Wb[t];                               // bypass weight rides in slot 9
    int coT = co >> 4, co16 = co & 15, ciH = ci >> 5, ci32 = ci & 31;
    dst = WffI + ((size_t)(((coT * 2 + ciH) * 16 + co16) * 32) + ci32) * 12;
  } else {
    const float* src = Wfb + (size_t)t * 9;
#pragma unroll
    for (int k = 0; k < 9; ++k) w[k] = src[8 - k];
    dst = WFlip + (size_t)t * 12;
  }
  float4 v0 = {w[0], w[1], w[2], w[3]};
  float4 v1 = {w[4], w[5], w[6], w[7]};
  float4 v2 = {w[8], w[9], w[10], w[11]};
  ((float4*)dst)[0] = v0; ((float4*)dst)[1] = v1; ((float4*)dst)[2] = v2;
}

// ---- conv3x2 (3x3, 2 och, 4 px); staged band pitch BP, input col j at j+2 ---
__device__ __forceinline__ void conv3x2(const float* __restrict__ buf,   // 4 planes x BPL
                                        const float* __restrict__ w0p,   // [ci][12]
                                        const float* __restrict__ w1p,
                                        int stci, int row_l, int c0,
                                        float a0[4], float a1[4]) {
#pragma unroll
  for (int cl = 0; cl < 4; ++cl) {
    float w0r[12], w1r[12];
    ldw12(w0p + (size_t)(stci + cl) * 12, w0r);
    ldw12(w1p + (size_t)(stci + cl) * 12, w1r);
    const float* pb = buf + cl * BPL;
#pragma unroll
    for (int di = 0; di < 3; ++di) {
      float f[8];
      ldrow8b(pb + (row_l + di) * BP + c0, f);
#pragma unroll
      for (int dj = 0; dj < 3; ++dj) {
        float wa = w0r[di * 3 + dj], wb = w1r[di * 3 + dj];
#pragma unroll
        for (int k = 0; k < 4; ++k) {
          a0[k] = fmaf(f[k + dj + 1], wa, a0[k]);
          a1[k] = fmaf(f[k + dj + 1], wb, a1[k]);
        }
      }
    }
  }
}

// bypass 1x1 accumulate from the staged band (interior row = row_l+1)
__device__ __forceinline__ void byp_acc(const float* __restrict__ buf,
                                        const float* __restrict__ w0p,
                                        const float* __restrict__ w1p,
                                        int stci, int row_l, int c0,
                                        float b0[4], float b1[4]) {
#pragma unroll
  for (int cl = 0; cl < 4; ++cl) {
    float wb0 = w0p[(size_t)(stci + cl) * 12 + 9];
    float wb1 = w1p[(size_t)(stci + cl) * 12 + 9];
    const float* rp = buf + cl * BPL + (row_l + 1) * BP + 2 + c0;
    float2 u = *(const float2*)rp;
    float2 v = *(const float2*)(rp + 2);
    float xf[4] = {u.x, u.y, v.x, v.y};
#pragma unroll
    for (int k = 0; k < 4; ++k) {
      b0[k] = fmaf(xf[k], wb0, b0[k]);
      b1[k] = fmaf(xf[k], wb1, b1[k]);
    }
  }
}

// ---- conv16: 5x5 over full-plane LDS buffer (pitch 44, halo+2), 16 px -------
__device__ __forceinline__ void conv16(const float* __restrict__ pb, const float w[28],
                                       int strip4, int cg4, float acc[16]) {
#pragma unroll
  for (int r = 0; r < 8; ++r) {
    float f[8];
    ldrow8b(pb + (strip4 + r) * 44 + cg4, f);
#pragma unroll
    for (int k = 0; k < 4; ++k) {
      int di = r - k;
      if (di >= 0 && di < 5) {
#pragma unroll
        for (int dj = 0; dj < 5; ++dj) {
          float wv = w[di * 5 + dj];
#pragma unroll
          for (int c = 0; c < 4; ++c)
            acc[k * 4 + c] = fmaf(f[c + dj], wv, acc[k * 4 + c]);
        }
      }
    }
  }
}

// ---- k_init_p: partial conv3x3(x,Wff) + partial 1x1 bypass over 32-ci half --
// grid 512 = b(2) | coT(3) | ciH(1) | band(3); block: 16 co x 4 rows x 32 cols
__global__ __launch_bounds__(256) void k_init_p(const float* __restrict__ x,
                                                const float* __restrict__ WffI,
                                                float* __restrict__ Q,
                                                float* __restrict__ Bq) {
  __shared__ __align__(16) float wS[6144];    // [16 co][32 ci][12] slot9=bypass
  __shared__ __align__(16) float sS[2304];    // [2][4 pl][6*BP]
  int tid = threadIdx.x, blk = blockIdx.x;
  int b = blk >> 7, coT = (blk >> 4) & 7, ciH = (blk >> 3) & 1, band = blk & 7;
  {
    const float4* src = (const float4*)(WffI + (size_t)(coT * 2 + ciH) * 6144);
    float4* d4 = (float4*)wS;
    for (int i = tid; i < 1536; i += 256) d4[i] = src[i];
  }
  for (int i = tid; i < 2304; i += 256) sS[i] = 0.f;
  int wv = tid >> 6, lane = tid & 63;
  int srow = lane >> 3, scol = lane & 7;
  int gr = band * 4 - 1 + srow;
  bool sv = (srow < 6) && (gr >= 0) && (gr < 32);
  const float* sbase = x + (size_t)(b * 64 + ciH * 32 + wv) * 1024 + gr * 32 + scol * 4;
  float* sd0 = sS + wv * BPL + srow * BP + 2 + scol * 4;
  int co2 = tid >> 5;
  int pg = tid & 31;
  int row_l = pg >> 3, c0 = (pg & 7) * 4;
  const float* w0p = wS + (size_t)(co2 * 2) * 384;
  const float* w1p = w0p + 384;
  float a0[4] = {0, 0, 0, 0}, a1[4] = {0, 0, 0, 0};
  float bb0[4] = {0, 0, 0, 0}, bb1[4] = {0, 0, 0, 0};
  float4 stg;
  if (sv) stg = *(const float4*)(sbase);
  __syncthreads();
  if (sv) stg_write(sd0, stg);
  __syncthreads();
  for (int st = 0; st < 8; st += 2) {
    if (sv) stg = *(const float4*)(sbase + (size_t)((st + 1) * 4) * 1024);
    conv3x2(sS, w0p, w1p, st * 4, row_l, c0, a0, a1);
    byp_acc(sS, w0p, w1p, st * 4, row_l, c0, bb0, bb1);
    if (sv) stg_write(sd0 + BDB, stg);
    __syncthreads();
    bool more = (st + 2 < 8);
    if (more && sv) stg = *(const float4*)(sbase + (size_t)((st + 2) * 4) * 1024);
    conv3x2(sS + BDB, w0p, w1p, (st + 1) * 4, row_l, c0, a0, a1);
    byp_acc(sS + BDB, w0p, w1p, (st + 1) * 4, row_l, c0, bb0, bb1);
    if (more && sv) stg_write(sd0, stg);
    __syncthreads();
  }
  int gi = band * 4 + row_l;
  int co = coT * 16 + co2 * 2;
  size_t off0 = (size_t)ciH * 524288 + (size_t)(b * 128 + co) * 1024 + gi * 32 + c0;
  size_t off1 = off0 + 1024;
  float4 o0 = {a0[0], a0[1], a0[2], a0[3]};
  float4 o1 = {a1[0], a1[1], a1[2], a1[3]};
  *(float4*)(Q + off0) = o0;
  *(float4*)(Q + off1) = o1;
  float4 bo0 = {bb0[0], bb0[1], bb0[2], bb0[3]};
  float4 bo1 = {bb1[0], bb1[1], bb1[2], bb1[3]};
  *(float4*)(Bq + off0) = bo0;
  *(float4*)(Bq + off1) = bo1;
}

// ---- k_rsum: yp0 = relu(Q0+Q1); Bp = B0+B1 ----------------------------------
__global__ __launch_bounds__(256) void k_rsum(const float* __restrict__ Q,
                                              const float* __restrict__ Bq,
                                              float* __restrict__ yp0,
                                              float* __restrict__ Bp) {
  size_t i = (size_t)(blockIdx.x * 256 + threadIdx.x) * 4;
  float4 a = *(const float4*)(Q + i);
  float4 b = *(const float4*)(Q + 524288 + i);
  float4 s = {a.x + b.x, a.y + b.y, a.z + b.z, a.w + b.w};
  float4 r = {s.x > 0.f ? s.x : 0.f, s.y > 0.f ? s.y : 0.f,
              s.z > 0.f ? s.z : 0.f, s.w > 0.f ? s.w : 0.f};
  *(float4*)(yp0 + i) = r;
  float4 u = *(const float4*)(Bq + i);
  float4 v = *(const float4*)(Bq + 524288 + i);
  float4 bp = {u.x + v.x, u.y + v.y, u.z + v.z, u.w + v.w};
  *(float4*)(Bp + i) = bp;
}

// ---- k_gram: 5x5 Gram of Wfb ------------------------------------------------
__global__ __launch_bounds__(256) void k_gram(const float* __restrict__ Wfb,
                                              float* __restrict__ G,
                                              float* __restrict__ Gam) {
  __shared__ float wA[128 * 9];
  __shared__ float gred[256][25];
  int tid = threadIdx.x;
  int op = blockIdx.x;
  if (blockIdx.x == 0 && tid < 16) Gam[tid] = 0.f;
  for (int i = tid; i < 1152; i += 256) {
    int c = i / 9, k = i - c * 9;
    wA[i] = Wfb[(size_t)(c * 64 + op) * 9 + k];
  }
  __syncthreads();
  int o = tid & 63, part = tid >> 6;
  float g[25];
#pragma unroll
  for (int i = 0; i < 25; ++i) g[i] = 0.f;
  for (int c = part * 32; c < part * 32 + 32; ++c) {
    float b9[9];
#pragma unroll
    for (int k = 0; k < 9; ++k) b9[k] = Wfb[(size_t)(c * 64 + o) * 9 + k];
    const float* a9 = &wA[c * 9];
#pragma unroll
    for (int ei = 0; ei < 3; ++ei)
#pragma unroll
      for (int ej = 0; ej < 3; ++ej) {
        float av = a9[ei * 3 + ej];
#pragma unroll
        for (int di = 0; di < 3; ++di)
#pragma unroll
          for (int dj = 0; dj < 3; ++dj)
            g[(ei - di + 2) * 5 + (ej - dj + 2)] = fmaf(av, b9[di * 3 + dj],
                                                        g[(ei - di + 2) * 5 + (ej - dj + 2)]);
      }
  }
#pragma unroll
  for (int i = 0; i < 25; ++i) gred[tid][i] = g[i];
  __syncthreads();
  if (part == 0) {
    float* dst = G + ((size_t)op * 64 + o) * 32;
#pragma unroll
    for (int i = 0; i < 25; ++i)
      dst[i] = gred[tid][i] + gred[tid + 64][i] + gred[tid + 128][i] + gred[tid + 192][i];
#pragma unroll
    for (int i = 25; i < 32; ++i) dst[i] = 0.f;
  }
}

// ---- k_forward: P[ciQ] = conv3x3 pad1(yp0[ciQ slice], WtF2) partials --------
__global__ __launch_bounds__(256) void k_forward(const float* __restrict__ yp0,
                                                 const float* __restrict__ WtF2,
                                                 float* __restrict__ Pn,
                                                 float* __restrict__ Pw) {
  __shared__ __align__(16) float wS[6144];    // [16 och][32 ci][12]
  __shared__ __align__(16) float sS[2304];
  int tid = threadIdx.x, blk = blockIdx.x;
  int b = blk >> 7, oT = (blk >> 5) & 3, ciQ = (blk >> 3) & 3, band = blk & 7;
  {
    const float4* src = (const float4*)(WtF2 + (size_t)(ciQ * 4 + oT) * 6144);
    float4* d4 = (float4*)wS;
    for (int i = tid; i < 1536; i += 256) d4[i] = src[i];
  }
  for (int i = tid; i < 2304; i += 256) sS[i] = 0.f;
  int wv = tid >> 6, lane = tid & 63;
  int srow = lane >> 3, scol = lane & 7;
  int gr = band * 4 - 1 + srow;
  bool sv = (srow < 6) && (gr >= 0) && (gr < 32);
  const float* sbase = yp0 + (size_t)(b * 128 + ciQ * 32 + wv) * 1024 + gr * 32 + scol * 4;
  float* sd0 = sS + wv * BPL + srow * BP + 2 + scol * 4;
  int co2 = tid >> 5;
  int pg = tid & 31;
  int row_l = pg >> 3, c0 = (pg & 7) * 4;
  const float* w0p = wS + (size_t)(co2 * 2) * 384;
  const float* w1p = w0p + 384;
  float a0[4] = {0, 0, 0, 0}, a1[4] = {0, 0, 0, 0};
  float4 stg;
  if (sv) stg = *(const float4*)(sbase);
  __syncthreads();
  if (sv) stg_write(sd0, stg);
  __syncthreads();
  for (int st = 0; st < 8; st += 2) {
    if (sv) stg = *(const float4*)(sbase + (size_t)((st + 1) * 4) * 1024);
    conv3x2(sS, w0p, w1p, st * 4, row_l, c0, a0, a1);
    if (sv) stg_write(sd0 + BDB, stg);
    __syncthreads();
    bool more = (st + 2 < 8);
    if (more && sv) stg = *(const float4*)(sbase + (size_t)((st + 2) * 4) * 1024);
    conv3x2(sS + BDB, w0p, w1p, (st + 1) * 4, row_l, c0, a0, a1);
    if (more && sv) stg_write(sd0, stg);
    __syncthreads();
  }
  int gi = band * 4 + row_l;
  int och = oT * 16 + co2 * 2;
  float* Pbase = (ciQ < 2) ? (Pn + (size_t)ciQ * 262144) : (Pw + (size_t)(ciQ - 2) * 262144);
  size_t off = (size_t)(b * 64 + och) * 1024 + gi * 32 + c0;
  float4 o0 = {a0[0], a0[1], a0[2], a0[3]};
  float4 o1 = {a1[0], a1[1], a1[2], a1[3]};
  *(float4*)(Pbase + off) = o0;
  *(float4*)(Pbase + off + 1024) = o1;
}

// ---- k_vsub: v0 = x - (P0+P1+P2+P3) -----------------------------------------
__global__ __launch_bounds__(256) void k_vsub(const float* __restrict__ x,
                                              const float* __restrict__ Pn,
                                              const float* __restrict__ Pw,
                                              float* __restrict__ v0) {
  size_t i = (size_t)(blockIdx.x * 256 + threadIdx.x) * 4;
  float4 xv = *(const float4*)(x + i);
  float4 p0 = *(const float4*)(Pn + i);
  float4 p1 = *(const float4*)(Pn + 262144 + i);
  float4 p2 = *(const float4*)(Pw + i);
  float4 p3 = *(const float4*)(Pw + 262144 + i);
  float4 r = {xv.x - p0.x - p1.x - p2.x - p3.x,
              xv.y - p0.y - p1.y - p2.y - p3.y,
              xv.z - p0.z - p1.z - p2.z - p3.z,
              xv.w - p0.w - p1.w - p2.w - p3.w};
  *(float4*)(v0 + i) = r;
}

// ---- k_applyGp: partial v_{j+1}[ciO] = G(*)v_j over 8-ci octant -------------
__global__ __launch_bounds__(256) void k_applyGp(const float* __restrict__ vin,
                                                 float* __restrict__ Pn,
                                                 float* __restrict__ Pw,
                                                 const float* __restrict__ G) {
  __shared__ __align__(16) float sS[3168];    // 2 x 36*44
  int tid = threadIdx.x, blk = blockIdx.x;
  int b = blk >> 7, ochQ = (blk >> 3) & 15, ciO = blk & 7;
  int wv = __builtin_amdgcn_readfirstlane(tid >> 6);
  int och = ochQ * 4 + wv;
  int strip4 = ((tid >> 3) & 7) * 4;
  int cg4 = (tid & 7) * 4;
  for (int i = tid; i < 3168; i += 256) sS[i] = 0.f;
  int srow = tid >> 3, scg = tid & 7;
  const float* sbase = vin + (size_t)(b * 64 + ciO * 8) * 1024 + srow * 32 + scg * 4;
  float* sd0 = sS + (srow + 2) * 44 + 2 + scg * 4;
  const float* gb = G + (size_t)och * 2048;
  float wA[28], wB[28];
  float acc[16];
#pragma unroll
  for (int i = 0; i < 16; ++i) acc[i] = 0.f;
  float4 stg = *(const float4*)(sbase);
  wload(gb, ciO * 8, wA);
  __syncthreads();
  stg_write(sd0, stg);
  __syncthreads();
  for (int ci = 0; ci < 8; ci += 2) {
    stg = *(const float4*)(sbase + (size_t)(ci + 1) * 1024);
    wload(gb, ciO * 8 + ci + 1, wB);
    conv16(sS, wA, strip4, cg4, acc);
    stg_write(sd0 + 1584, stg);
    __syncthreads();
    bool more = (ci + 2 < 8);
    if (more) {
      stg = *(const float4*)(sbase + (size_t)(ci + 2) * 1024);
      wload(gb, ciO * 8 + ci + 2, wA);
    }
    conv16(sS + 1584, wB, strip4, cg4, acc);
    if (more) stg_write(sd0, stg);
    __syncthreads();
  }
  float* Pbase = (ciO < 2) ? (Pn + (size_t)ciO * 262144) : (Pw + (size_t)(ciO - 2) * 262144);
  float* dst = Pbase + (size_t)(b * 64 + och) * 1024 + strip4 * 32 + cg4;
#pragma unroll
  for (int k = 0; k < 4; ++k) {
    float4 o = {acc[k * 4], acc[k * 4 + 1], acc[k * 4 + 2], acc[k * 4 + 3]};
    *(float4*)(dst + k * 32) = o;
  }
}

// ---- k_sum8: vout = sum of 8 partials ---------------------------------------
__global__ __launch_bounds__(256) void k_sum8(const float* __restrict__ Pn,
                                              const float* __restrict__ Pw,
                                              float* __restrict__ vout) {
  size_t i = (size_t)(blockIdx.x * 256 + threadIdx.x) * 4;
  float4 s = *(const float4*)(Pn + i);
  float4 p = *(const float4*)(Pn + 262144 + i);
  s.x += p.x; s.y += p.y; s.z += p.z; s.w += p.w;
#pragma unroll
  for (int o = 0; o < 6; ++o) {
    float4 q = *(const float4*)(Pw + (size_t)o * 262144 + i);
    s.x += q.x; s.y += q.y; s.z += q.z; s.w += q.w;
  }
  *(float4*)(vout + i) = s;
}

// ---- k_gamma ----------------------------------------------------------------
__global__ __launch_bounds__(256) void k_gamma(const float* __restrict__ V,
                                               float* __restrict__ Gam) {
  __shared__ float ws4[4];
  int tid = threadIdx.x;
  int p = blockIdx.x >> 3, slice = blockIdx.x & 7;
  int i = 0, rem = p;
  while (rem >= KRYLOV - i) { rem -= KRYLOV - i; ++i; }
  int j = i + rem;
  const float4* vi = (const float4*)(V + (size_t)i * VPLANE);
  const float4* vj = (const float4*)(V + (size_t)j * VPLANE);
  int base = slice * 8192;
  float acc = 0.f;
  for (int t = tid; t < 8192; t += 256) {
    float4 a = vi[base + t], c = vj[base + t];
    acc = fmaf(a.x, c.x, acc);
    acc = fmaf(a.y, c.y, acc);
    acc = fmaf(a.z, c.z, acc);
    acc = fmaf(a.w, c.w, acc);
  }
#pragma unroll
  for (int d = 32; d; d >>= 1) acc += __shfl_down(acc, d, 64);
  if ((tid & 63) == 0) ws4[tid >> 6] = acc;
  __syncthreads();
  if (tid == 0) {
    float tot = ws4[0] + ws4[1] + ws4[2] + ws4[3];
    atomicAdd(&Gam[i * KRYLOV + j], tot);
    if (i != j) atomicAdd(&Gam[j * KRYLOV + i], tot);
  }
}

// ---- k_scalar ---------------------------------------------------------------
__global__ __launch_bounds__(64) void k_scalar(const float* __restrict__ Gam,
                                               float* __restrict__ dvec) {
  float g00 = Gam[0], g01 = Gam[1], g02 = Gam[2];
  float g11 = Gam[4], g12 = Gam[5], g22 = Gam[8];
  float c0 = 1.f, c1 = 0.f, c2 = 0.f;
  float d0 = 0.f, d1 = 0.f, d2 = 0.f;
#pragma unroll
  for (int seg = 0; seg < 20; ++seg) {
    float pr = g00 * c0 * c0 + g11 * c1 * c1 + g22 * c2 * c2 +
               2.f * (g01 * c0 * c1 + g02 * c0 * c2 + g12 * c1 * c2);
    float a = LR_F * __builtin_amdgcn_rsqf(pr);
    float a2 = a * a, a3 = a2 * a;
    d0 += 25.f * a * c0;
    d1 += 25.f * a * c1 - 300.f * a2 * c0;
    d2 += 25.f * a * c2 - 300.f * a2 * c1 + 2300.f * a3 * c0;
    float t1 = c1 - 25.f * a * c0;
    float t2 = c2 - 25.f * a * c1 + 300.f * a2 * c0;
    c1 = t1; c2 = t2;
  }
  if (threadIdx.x == 0) { dvec[0] = d0; dvec[1] = d1; dvec[2] = d2; }
}

// ---- k_combine --------------------------------------------------------------
__global__ __launch_bounds__(256) void k_combine(float* __restrict__ V,
                                                 const float* __restrict__ dvec) {
  int idx = blockIdx.x * 256 + threadIdx.x;
  float d[KRYLOV];
#pragma unroll
  for (int i = 0; i < KRYLOV; ++i) d[i] = dvec[i];
  float4 acc = {0.f, 0.f, 0.f, 0.f};
#pragma unroll
  for (int i = 0; i < KRYLOV; ++i) {
    float4 v = *(const float4*)(V + (size_t)i * VPLANE + (size_t)idx * 4);
    acc.x = fmaf(d[i], v.x, acc.x);
    acc.y = fmaf(d[i], v.y, acc.y);
    acc.z = fmaf(d[i], v.z, acc.z);
    acc.w = fmaf(d[i], v.w, acc.w);
  }
  *(float4*)(V + (size_t)idx * 4) = acc;
}

// ---- k_finalize: out = yp0 + conv3x3 pad1(s, WFlip) + Bp --------------------
__global__ __launch_bounds__(256) void k_finalize(const float* __restrict__ WFlip,
                                                  const float* __restrict__ yp0,
                                                  const float* __restrict__ s,
                                                  const float* __restrict__ Bp,
                                                  float* __restrict__ out) {
  __shared__ __align__(16) float wS[12288];   // [16 co][64 ci][12]
  __shared__ __align__(16) float sS[2304];
  int tid = threadIdx.x, blk = blockIdx.x;
  int b = blk >> 6, coT = (blk >> 3) & 7, band = blk & 7;
  {
    const float4* src = (const float4*)(WFlip + (size_t)coT * 12288);
    float4* d4 = (float4*)wS;
    for (int i = tid; i < 3072; i += 256) d4[i] = src[i];
  }
  for (int i = tid; i < 2304; i += 256) sS[i] = 0.f;
  int wv = tid >> 6, lane = tid & 63;
  int srow = lane >> 3, scol = lane & 7;
  int gr = band * 4 - 1 + srow;
  bool sv = (srow < 6) && (gr >= 0) && (gr < 32);
  const float* sbase = s + (size_t)(b * 64 + wv) * 1024 + gr * 32 + scol * 4;
  float* sd0 = sS + wv * BPL + srow * BP + 2 + scol * 4;
  int co2 = tid >> 5;
  int pg = tid & 31;
  int row_l = pg >> 3, c0 = (pg & 7) * 4;
  const float* w0p = wS + (size_t)(co2 * 2) * 768;
  const float* w1p = w0p + 768;
  float a0[4] = {0, 0, 0, 0}, a1[4] = {0, 0, 0, 0};
  float4 stg;
  if (sv) stg = *(const float4*)(sbase);
  __syncthreads();
  if (sv) stg_write(sd0, stg);
  __syncthreads();
  for (int st = 0; st < 16; st += 2) {
    if (sv) stg = *(const float4*)(sbase + (size_t)((st + 1) * 4) * 1024);
    conv3x2(sS, w0p, w1p, st * 4, row_l, c0, a0, a1);
    if (sv) stg_write(sd0 + BDB, stg);
    __syncthreads();
    bool more = (st + 2 < 16);
    if (more && sv) stg = *(const float4*)(sbase + (size_t)((st + 2) * 4) * 1024);
    conv3x2(sS + BDB, w0p, w1p, (st + 1) * 4, row_l, c0, a0, a1);
    if (more && sv) stg_write(sd0, stg);
    __syncthreads();
  }
  int gi = band * 4 + row_l;
  int co = coT * 16 + co2 * 2;
  size_t off0 = (size_t)(b * 128 + co) * 1024 + gi * 32 + c0;
  size_t off1 = off0 + 1024;
  float4 y0 = *(const float4*)(yp0 + off0);
  float4 y1 = *(const float4*)(yp0 + off1);
  float4 bp0 = *(const float4*)(Bp + off0);    // same-thread read of d_out slot
  float4 bp1 = *(const float4*)(Bp + off1);
  float4 o0 = {a0[0] + y0.x + bp0.x, a0[1] + y0.y + bp0.y,
               a0[2] + y0.z + bp0.z, a0[3] + y0.w + bp0.w};
  float4 o1 = {a1[0] + y1.x + bp1.x, a1[1] + y1.y + bp1.y,
               a1[2] + y1.z + bp1.z, a1[3] + y1.w + bp1.w};
  *(float4*)(out + off0) = o0;
  *(float4*)(out + off1) = o1;
}

// ---- launch -----------------------------------------------------------------
extern "C" void kernel_launch(void* const* d_in, const int* in_sizes, int n_in,
                              void* d_out, int out_size, void* d_ws, size_t ws_size,
                              hipStream_t stream) {
  const float* x   = (const float*)d_in[0];
  const float* Wff = (const float*)d_in[1];
  const float* Wfb = (const float*)d_in[2];
  const float* Wb  = (const float*)d_in[3];
  float* out = (float*)d_out;

  float* yp0   = (float*)d_ws;                 // 524288
  float* V     = yp0 + 524288;                 // 3 * 262144
  float* G5    = V + (size_t)KRYLOV * VPLANE;  // 131072
  float* Gam   = G5 + 131072;                  // 16
  float* dvec  = Gam + 16;                     // 16
  float* WFlip = dvec + 16;                    // 98304
  float* Pw    = WFlip + 98304;                // 6 * 262144 (P slots 2-7)
  float* WffI  = Pw + (size_t)6 * 262144;      // 98304
  float* WtF2  = WffI + 98304;                 // 98304
  float* Pn    = WtF2 + 98304;                 // 2 * 262144 (P slots 0-1)
  float* Q     = Pn + (size_t)2 * 262144;      // 2 * 524288 (init partials)
  float* Bq    = Q + (size_t)2 * 524288;       // 2 * 524288 (bypass partials)
  float* Bp    = out;                          // bypass planes in d_out

  hipLaunchKernelGGL(k_prep,    dim3(96),  dim3(256), 0, stream, Wff, Wfb, Wb, WffI, WtF2, WFlip);
  hipLaunchKernelGGL(k_init_p,  dim3(512), dim3(256), 0, stream, x, WffI, Q, Bq);
  hipLaunchKernelGGL(k_rsum,    dim3(512), dim3(256), 0, stream, Q, Bq, yp0, Bp);
  hipLaunchKernelGGL(k_gram,    dim3(64),  dim3(256), 0, stream, Wfb, G5, Gam);
  hipLaunchKernelGGL(k_forward, dim3(512), dim3(256), 0, stream, yp0, WtF2, Pn, Pw);
  hipLaunchKernelGGL(k_vsub,    dim3(256), dim3(256), 0, stream, x, Pn, Pw, V);
  hipLaunchKernelGGL(k_applyGp, dim3(512), dim3(256), 0, stream, V, Pn, Pw, G5);
  hipLaunchKernelGGL(k_sum8,    dim3(256), dim3(256), 0, stream, Pn, Pw, V + VPLANE);
  hipLaunchKernelGGL(k_applyGp, dim3(512), dim3(256), 0, stream, V + VPLANE, Pn, Pw, G5);
  hipLaunchKernelGGL(k_sum8,    dim3(256), dim3(256), 0, stream, Pn, Pw, V + 2 * VPLANE);
  hipLaunchKernelGGL(k_gamma,   dim3(48),  dim3(256), 0, stream, V, Gam);
  hipLaunchKernelGGL(k_scalar,  dim3(1),   dim3(64),  0, stream, Gam, dvec);
  hipLaunchKernelGGL(k_combine, dim3(256), dim3(256), 0, stream, V, dvec);
  hipLaunchKernelGGL(k_finalize, dim3(256), dim3(256), 0, stream, WFlip, yp0, V, Bp, out);
}

// Round 12
// 225.380 us; speedup vs baseline: 1.1071x; 1.1071x over previous
//
#include <hip/hip_runtime.h>

#define NUM_ITERS 500
#define LR_F 0.001f
#define KRYLOV 3
#define VPLANE 262144    // 4*64*1024 floats per Krylov vector
// 500 = 20 segments * 25 steps; C(25,1)=25, C(25,2)=300, C(25,3)=2300

// ---- register-safe unpack helpers -------------------------------------------
// aligned b128 pair: f[0..7] = LDS words rp..rp+7 (rp 4-word aligned)
__device__ __forceinline__ void ldrow8b(const float* __restrict__ rp, float f[8]) {
  float4 a = *(const float4*)(rp);
  float4 b = *(const float4*)(rp + 4);
  f[0] = a.x; f[1] = a.y; f[2] = a.z; f[3] = a.w;
  f[4] = b.x; f[5] = b.y; f[6] = b.z; f[7] = b.w;
}

// 25 (padded 28) weights for row o from table base (stride 32, 16B aligned)
__device__ __forceinline__ void wload(const float* __restrict__ gb, int o, float w[28]) {
  const float4* g4 = (const float4*)(gb + o * 32);
#pragma unroll
  for (int i = 0; i < 7; ++i) {
    float4 v = g4[i];
    w[4 * i] = v.x; w[4 * i + 1] = v.y; w[4 * i + 2] = v.z; w[4 * i + 3] = v.w;
  }
}

// 12 weights (9 taps + slot9) from stride-16 table, wave-uniform global load
__device__ __forceinline__ void wload3(const float* __restrict__ wb, int ci, float w[12]) {
  const float4* g4 = (const float4*)(wb + (size_t)ci * 16);
  float4 a = g4[0], b = g4[1], c = g4[2];
  w[0] = a.x; w[1] = a.y; w[2] = a.z; w[3] = a.w;
  w[4] = b.x; w[5] = b.y; w[6] = b.z; w[7] = b.w;
  w[8] = c.x; w[9] = c.y; w[10] = c.z; w[11] = c.w;
}

// staging write helper: float4 -> LDS word addr == 2 (mod 4), as two float2
__device__ __forceinline__ void stg_write(float* sd, float4 v) {
  float2 u = {v.x, v.y}, w = {v.z, v.w};
  *(float2*)sd = u;
  *(float2*)(sd + 2) = w;
}

// ---- weight prep: three stride-16 tables ------------------------------------
// WF[o(64)][c(128)][16] = Wfb[(c*64+o)*9+k]        (forward, transposed)
// WI[co(128)][ci(64)][16] = Wff[...*9+k], slot9=Wb (init + bypass)
// WZ[co(128)][ci(64)][16] = Wfb[...*9 + 8-k]       (finalize, flipped)
__global__ __launch_bounds__(256) void k_prep(const float* __restrict__ Wff,
                                              const float* __restrict__ Wfb,
                                              const float* __restrict__ Wb,
                                              float* __restrict__ WI,
                                              float* __restrict__ WF,
                                              float* __restrict__ WZ) {
  int g = blockIdx.x * 256 + threadIdx.x;
  int table = g >> 13, t = g & 8191;
  float w[16];
#pragma unroll
  for (int k = 0; k < 16; ++k) w[k] = 0.f;
  float* dst;
  if (table == 0) {
    int o = t >> 7, c = t & 127;
    const float* src = Wfb + (size_t)(c * 64 + o) * 9;
#pragma unroll
    for (int k = 0; k < 9; ++k) w[k] = src[k];
    dst = WF + (size_t)(o * 128 + c) * 16;
  } else if (table == 1) {
    const float* src = Wff + (size_t)t * 9;
#pragma unroll
    for (int k = 0; k < 9; ++k) w[k] = src[k];
    w[9] = Wb[t];
    dst = WI + (size_t)t * 16;
  } else {
    const float* src = Wfb + (size_t)t * 9;
#pragma unroll
    for (int k = 0; k < 9; ++k) w[k] = src[8 - k];
    dst = WZ + (size_t)t * 16;
  }
  float4 v0 = {w[0], w[1], w[2], w[3]};
  float4 v1 = {w[4], w[5], w[6], w[7]};
  float4 v2 = {w[8], w[9], w[10], w[11]};
  float4 v3 = {w[12], w[13], w[14], w[15]};
  ((float4*)dst)[0] = v0; ((float4*)dst)[1] = v1;
  ((float4*)dst)[2] = v2; ((float4*)dst)[3] = v3;
}

// ---- conv16_3: 3x3 pad1 over full-plane LDS (pitch 44, halo+2), 16 px -------
// out(R,C) = sum_{di,dj in 0..2} w[di*3+dj] * in(R+di-1, C+dj-1)
// R=strip4+k, C=cg4+c. LDS row = in_row+2, col = in_col+2.
// Read row r: LDS row strip4+1+r (in rows strip4-1..+4); f[m] = in col cg4+m-2.
// Tap needs r=k+di, m=c+dj+1. Bypass (slot 9): center row di==1, m=c+2.
template <bool BYP>
__device__ __forceinline__ void conv16_3(const float* __restrict__ pb, const float w[12],
                                         int strip4, int cg4, float acc[16], float by[16]) {
  float wb = w[9];
#pragma unroll
  for (int r = 0; r < 6; ++r) {
    float f[8];
    ldrow8b(pb + (strip4 + 1 + r) * 44 + cg4, f);
#pragma unroll
    for (int k = 0; k < 4; ++k) {
      int di = r - k;
      if (di >= 0 && di < 3) {
#pragma unroll
        for (int dj = 0; dj < 3; ++dj) {
          float wv = w[di * 3 + dj];
#pragma unroll
          for (int c = 0; c < 4; ++c)
            acc[k * 4 + c] = fmaf(f[c + dj + 1], wv, acc[k * 4 + c]);
        }
        if (BYP && di == 1) {
#pragma unroll
          for (int c = 0; c < 4; ++c)
            by[k * 4 + c] = fmaf(f[c + 2], wb, by[k * 4 + c]);
        }
      }
    }
  }
}

// ---- conv16: 5x5 over full-plane LDS buffer (pitch 44, halo+2), 16 px -------
__device__ __forceinline__ void conv16(const float* __restrict__ pb, const float w[28],
                                       int strip4, int cg4, float acc[16]) {
#pragma unroll
  for (int r = 0; r < 8; ++r) {
    float f[8];
    ldrow8b(pb + (strip4 + r) * 44 + cg4, f);
#pragma unroll
    for (int k = 0; k < 4; ++k) {
      int di = r - k;
      if (di >= 0 && di < 5) {
#pragma unroll
        for (int dj = 0; dj < 5; ++dj) {
          float wv = w[di * 5 + dj];
#pragma unroll
          for (int c = 0; c < 4; ++c)
            acc[k * 4 + c] = fmaf(f[c + dj], wv, acc[k * 4 + c]);
        }
      }
    }
  }
}

// ---- k_init_p: partial conv3x3(x,WI) + partial bypass over 16-ci quarter ----
// grid 512 = b(2) | ochQ(5) | ciQ(2); block: 4 och (wave-uniform) x 16 px/thr
__global__ __launch_bounds__(256) void k_init_p(const float* __restrict__ x,
                                                const float* __restrict__ WI,
                                                float* __restrict__ Q,
                                                float* __restrict__ Bq) {
  __shared__ __align__(16) float sS[3168];    // 2 x 36*44
  int tid = threadIdx.x, blk = blockIdx.x;
  int b = blk >> 7, ochQ = (blk >> 2) & 31, ciQ = blk & 3;
  int wv = __builtin_amdgcn_readfirstlane(tid >> 6);
  int och = ochQ * 4 + wv;                    // 0..127
  int strip4 = ((tid >> 3) & 7) * 4;
  int cg4 = (tid & 7) * 4;
  for (int i = tid; i < 3168; i += 256) sS[i] = 0.f;
  int srow = tid >> 3, scg = tid & 7;
  const float* sbase = x + (size_t)(b * 64 + ciQ * 16) * 1024 + srow * 32 + scg * 4;
  float* sd0 = sS + (srow + 2) * 44 + 2 + scg * 4;
  const float* wb_base = WI + (size_t)och * 64 * 16;
  float wA[12], wB[12];
  float acc[16], by[16];
#pragma unroll
  for (int i = 0; i < 16; ++i) { acc[i] = 0.f; by[i] = 0.f; }
  float4 stg = *(const float4*)(sbase);
  wload3(wb_base, ciQ * 16, wA);
  __syncthreads();
  stg_write(sd0, stg);
  __syncthreads();
  for (int ci = 0; ci < 16; ci += 2) {
    stg = *(const float4*)(sbase + (size_t)(ci + 1) * 1024);
    wload3(wb_base, ciQ * 16 + ci + 1, wB);
    conv16_3<true>(sS, wA, strip4, cg4, acc, by);
    stg_write(sd0 + 1584, stg);
    __syncthreads();
    bool more = (ci + 2 < 16);
    if (more) {
      stg = *(const float4*)(sbase + (size_t)(ci + 2) * 1024);
      wload3(wb_base, ciQ * 16 + ci + 2, wA);
    }
    conv16_3<true>(sS + 1584, wB, strip4, cg4, acc, by);
    if (more) stg_write(sd0, stg);
    __syncthreads();
  }
  size_t off = (size_t)ciQ * 524288 + (size_t)(b * 128 + och) * 1024 + strip4 * 32 + cg4;
#pragma unroll
  for (int k = 0; k < 4; ++k) {
    float4 o = {acc[k * 4], acc[k * 4 + 1], acc[k * 4 + 2], acc[k * 4 + 3]};
    float4 bo = {by[k * 4], by[k * 4 + 1], by[k * 4 + 2], by[k * 4 + 3]};
    *(float4*)(Q + off + k * 32) = o;
    *(float4*)(Bq + off + k * 32) = bo;
  }
}

// ---- k_rsum: yp0 = relu(sum Q); Bp = sum Bq ---------------------------------
__global__ __launch_bounds__(256) void k_rsum(const float* __restrict__ Q,
                                              const float* __restrict__ Bq,
                                              float* __restrict__ yp0,
                                              float* __restrict__ Bp) {
  size_t i = (size_t)(blockIdx.x * 256 + threadIdx.x) * 4;
  float4 s = {0.f, 0.f, 0.f, 0.f}, t = {0.f, 0.f, 0.f, 0.f};
#pragma unroll
  for (int q = 0; q < 4; ++q) {
    float4 a = *(const float4*)(Q + (size_t)q * 524288 + i);
    float4 b = *(const float4*)(Bq + (size_t)q * 524288 + i);
    s.x += a.x; s.y += a.y; s.z += a.z; s.w += a.w;
    t.x += b.x; t.y += b.y; t.z += b.z; t.w += b.w;
  }
  float4 r = {s.x > 0.f ? s.x : 0.f, s.y > 0.f ? s.y : 0.f,
              s.z > 0.f ? s.z : 0.f, s.w > 0.f ? s.w : 0.f};
  *(float4*)(yp0 + i) = r;
  *(float4*)(Bp + i) = t;
}

// ---- k_gram: 5x5 Gram of Wfb ------------------------------------------------
__global__ __launch_bounds__(256) void k_gram(const float* __restrict__ Wfb,
                                              float* __restrict__ G,
                                              float* __restrict__ Gam) {
  __shared__ float wA[128 * 9];
  __shared__ float gred[256][25];
  int tid = threadIdx.x;
  int op = blockIdx.x;
  if (blockIdx.x == 0 && tid < 16) Gam[tid] = 0.f;
  for (int i = tid; i < 1152; i += 256) {
    int c = i / 9, k = i - c * 9;
    wA[i] = Wfb[(size_t)(c * 64 + op) * 9 + k];
  }
  __syncthreads();
  int o = tid & 63, part = tid >> 6;
  float g[25];
#pragma unroll
  for (int i = 0; i < 25; ++i) g[i] = 0.f;
  for (int c = part * 32; c < part * 32 + 32; ++c) {
    float b9[9];
#pragma unroll
    for (int k = 0; k < 9; ++k) b9[k] = Wfb[(size_t)(c * 64 + o) * 9 + k];
    const float* a9 = &wA[c * 9];
#pragma unroll
    for (int ei = 0; ei < 3; ++ei)
#pragma unroll
      for (int ej = 0; ej < 3; ++ej) {
        float av = a9[ei * 3 + ej];
#pragma unroll
        for (int di = 0; di < 3; ++di)
#pragma unroll
          for (int dj = 0; dj < 3; ++dj)
            g[(ei - di + 2) * 5 + (ej - dj + 2)] = fmaf(av, b9[di * 3 + dj],
                                                        g[(ei - di + 2) * 5 + (ej - dj + 2)]);
      }
  }
#pragma unroll
  for (int i = 0; i < 25; ++i) gred[tid][i] = g[i];
  __syncthreads();
  if (part == 0) {
    float* dst = G + ((size_t)op * 64 + o) * 32;
#pragma unroll
    for (int i = 0; i < 25; ++i)
      dst[i] = gred[tid][i] + gred[tid + 64][i] + gred[tid + 128][i] + gred[tid + 192][i];
#pragma unroll
    for (int i = 25; i < 32; ++i) dst[i] = 0.f;
  }
}

// ---- k_forward_p: partial conv3x3(yp0, WF) over 16-ci octant ----------------
// grid 512 = b(2) | ochQ(4) | ciO(3); partials in Pn(0-1)/Pw(2-7)
__global__ __launch_bounds__(256) void k_forward_p(const float* __restrict__ yp0,
                                                   const float* __restrict__ WF,
                                                   float* __restrict__ Pn,
                                                   float* __restrict__ Pw) {
  __shared__ __align__(16) float sS[3168];
  int tid = threadIdx.x, blk = blockIdx.x;
  int b = blk >> 7, ochQ = (blk >> 3) & 15, ciO = blk & 7;
  int wv = __builtin_amdgcn_readfirstlane(tid >> 6);
  int och = ochQ * 4 + wv;                    // 0..63
  int strip4 = ((tid >> 3) & 7) * 4;
  int cg4 = (tid & 7) * 4;
  for (int i = tid; i < 3168; i += 256) sS[i] = 0.f;
  int srow = tid >> 3, scg = tid & 7;
  const float* sbase = yp0 + (size_t)(b * 128 + ciO * 16) * 1024 + srow * 32 + scg * 4;
  float* sd0 = sS + (srow + 2) * 44 + 2 + scg * 4;
  const float* wb_base = WF + (size_t)och * 128 * 16;
  float wA[12], wB[12];
  float acc[16], dummy[16];
#pragma unroll
  for (int i = 0; i < 16; ++i) acc[i] = 0.f;
  float4 stg = *(const float4*)(sbase);
  wload3(wb_base, ciO * 16, wA);
  __syncthreads();
  stg_write(sd0, stg);
  __syncthreads();
  for (int ci = 0; ci < 16; ci += 2) {
    stg = *(const float4*)(sbase + (size_t)(ci + 1) * 1024);
    wload3(wb_base, ciO * 16 + ci + 1, wB);
    conv16_3<false>(sS, wA, strip4, cg4, acc, dummy);
    stg_write(sd0 + 1584, stg);
    __syncthreads();
    bool more = (ci + 2 < 16);
    if (more) {
      stg = *(const float4*)(sbase + (size_t)(ci + 2) * 1024);
      wload3(wb_base, ciO * 16 + ci + 2, wA);
    }
    conv16_3<false>(sS + 1584, wB, strip4, cg4, acc, dummy);
    if (more) stg_write(sd0, stg);
    __syncthreads();
  }
  float* Pbase = (ciO < 2) ? (Pn + (size_t)ciO * 262144) : (Pw + (size_t)(ciO - 2) * 262144);
  float* dst = Pbase + (size_t)(b * 64 + och) * 1024 + strip4 * 32 + cg4;
#pragma unroll
  for (int k = 0; k < 4; ++k) {
    float4 o = {acc[k * 4], acc[k * 4 + 1], acc[k * 4 + 2], acc[k * 4 + 3]};
    *(float4*)(dst + k * 32) = o;
  }
}

// ---- k_vsub: v0 = x - (P0+P1+P2+...+P7) -------------------------------------
__global__ __launch_bounds__(256) void k_vsub(const float* __restrict__ x,
                                              const float* __restrict__ Pn,
                                              const float* __restrict__ Pw,
                                              float* __restrict__ v0) {
  size_t i = (size_t)(blockIdx.x * 256 + threadIdx.x) * 4;
  float4 xv = *(const float4*)(x + i);
  float4 s = {0.f, 0.f, 0.f, 0.f};
#pragma unroll
  for (int o = 0; o < 2; ++o) {
    float4 p = *(const float4*)(Pn + (size_t)o * 262144 + i);
    s.x += p.x; s.y += p.y; s.z += p.z; s.w += p.w;
  }
#pragma unroll
  for (int o = 0; o < 6; ++o) {
    float4 p = *(const float4*)(Pw + (size_t)o * 262144 + i);
    s.x += p.x; s.y += p.y; s.z += p.z; s.w += p.w;
  }
  float4 r = {xv.x - s.x, xv.y - s.y, xv.z - s.z, xv.w - s.w};
  *(float4*)(v0 + i) = r;
}

// ---- k_applyGp: partial v_{j+1}[ciO] = G(*)v_j over 8-ci octant -------------
__global__ __launch_bounds__(256) void k_applyGp(const float* __restrict__ vin,
                                                 float* __restrict__ Pn,
                                                 float* __restrict__ Pw,
                                                 const float* __restrict__ G) {
  __shared__ __align__(16) float sS[3168];    // 2 x 36*44
  int tid = threadIdx.x, blk = blockIdx.x;
  int b = blk >> 7, ochQ = (blk >> 3) & 15, ciO = blk & 7;
  int wv = __builtin_amdgcn_readfirstlane(tid >> 6);
  int och = ochQ * 4 + wv;
  int strip4 = ((tid >> 3) & 7) * 4;
  int cg4 = (tid & 7) * 4;
  for (int i = tid; i < 3168; i += 256) sS[i] = 0.f;
  int srow = tid >> 3, scg = tid & 7;
  const float* sbase = vin + (size_t)(b * 64 + ciO * 8) * 1024 + srow * 32 + scg * 4;
  float* sd0 = sS + (srow + 2) * 44 + 2 + scg * 4;
  const float* gb = G + (size_t)och * 2048;
  float wA[28], wB[28];
  float acc[16];
#pragma unroll
  for (int i = 0; i < 16; ++i) acc[i] = 0.f;
  float4 stg = *(const float4*)(sbase);
  wload(gb, ciO * 8, wA);
  __syncthreads();
  stg_write(sd0, stg);
  __syncthreads();
  for (int ci = 0; ci < 8; ci += 2) {
    stg = *(const float4*)(sbase + (size_t)(ci + 1) * 1024);
    wload(gb, ciO * 8 + ci + 1, wB);
    conv16(sS, wA, strip4, cg4, acc);
    stg_write(sd0 + 1584, stg);
    __syncthreads();
    bool more = (ci + 2 < 8);
    if (more) {
      stg = *(const float4*)(sbase + (size_t)(ci + 2) * 1024);
      wload(gb, ciO * 8 + ci + 2, wA);
    }
    conv16(sS + 1584, wB, strip4, cg4, acc);
    if (more) stg_write(sd0, stg);
    __syncthreads();
  }
  float* Pbase = (ciO < 2) ? (Pn + (size_t)ciO * 262144) : (Pw + (size_t)(ciO - 2) * 262144);
  float* dst = Pbase + (size_t)(b * 64 + och) * 1024 + strip4 * 32 + cg4;
#pragma unroll
  for (int k = 0; k < 4; ++k) {
    float4 o = {acc[k * 4], acc[k * 4 + 1], acc[k * 4 + 2], acc[k * 4 + 3]};
    *(float4*)(dst + k * 32) = o;
  }
}

// ---- k_sum8: vout = sum of 8 partials ---------------------------------------
__global__ __launch_bounds__(256) void k_sum8(const float* __restrict__ Pn,
                                              const float* __restrict__ Pw,
                                              float* __restrict__ vout) {
  size_t i = (size_t)(blockIdx.x * 256 + threadIdx.x) * 4;
  float4 s = *(const float4*)(Pn + i);
  float4 p = *(const float4*)(Pn + 262144 + i);
  s.x += p.x; s.y += p.y; s.z += p.z; s.w += p.w;
#pragma unroll
  for (int o = 0; o < 6; ++o) {
    float4 q = *(const float4*)(Pw + (size_t)o * 262144 + i);
    s.x += q.x; s.y += q.y; s.z += q.z; s.w += q.w;
  }
  *(float4*)(vout + i) = s;
}

// ---- k_gamma ----------------------------------------------------------------
__global__ __launch_bounds__(256) void k_gamma(const float* __restrict__ V,
                                               float* __restrict__ Gam) {
  __shared__ float ws4[4];
  int tid = threadIdx.x;
  int p = blockIdx.x >> 3, slice = blockIdx.x & 7;
  int i = 0, rem = p;
  while (rem >= KRYLOV - i) { rem -= KRYLOV - i; ++i; }
  int j = i + rem;
  const float4* vi = (const float4*)(V + (size_t)i * VPLANE);
  const float4* vj = (const float4*)(V + (size_t)j * VPLANE);
  int base = slice * 8192;
  float acc = 0.f;
  for (int t = tid; t < 8192; t += 256) {
    float4 a = vi[base + t], c = vj[base + t];
    acc = fmaf(a.x, c.x, acc);
    acc = fmaf(a.y, c.y, acc);
    acc = fmaf(a.z, c.z, acc);
    acc = fmaf(a.w, c.w, acc);
  }
#pragma unroll
  for (int d = 32; d; d >>= 1) acc += __shfl_down(acc, d, 64);
  if ((tid & 63) == 0) ws4[tid >> 6] = acc;
  __syncthreads();
  if (tid == 0) {
    float tot = ws4[0] + ws4[1] + ws4[2] + ws4[3];
    atomicAdd(&Gam[i * KRYLOV + j], tot);
    if (i != j) atomicAdd(&Gam[j * KRYLOV + i], tot);
  }
}

// ---- k_scalar ---------------------------------------------------------------
__global__ __launch_bounds__(64) void k_scalar(const float* __restrict__ Gam,
                                               float* __restrict__ dvec) {
  float g00 = Gam[0], g01 = Gam[1], g02 = Gam[2];
  float g11 = Gam[4], g12 = Gam[5], g22 = Gam[8];
  float c0 = 1.f, c1 = 0.f, c2 = 0.f;
  float d0 = 0.f, d1 = 0.f, d2 = 0.f;
#pragma unroll
  for (int seg = 0; seg < 20; ++seg) {
    float pr = g00 * c0 * c0 + g11 * c1 * c1 + g22 * c2 * c2 +
               2.f * (g01 * c0 * c1 + g02 * c0 * c2 + g12 * c1 * c2);
    float a = LR_F * __builtin_amdgcn_rsqf(pr);
    float a2 = a * a, a3 = a2 * a;
    d0 += 25.f * a * c0;
    d1 += 25.f * a * c1 - 300.f * a2 * c0;
    d2 += 25.f * a * c2 - 300.f * a2 * c1 + 2300.f * a3 * c0;
    float t1 = c1 - 25.f * a * c0;
    float t2 = c2 - 25.f * a * c1 + 300.f * a2 * c0;
    c1 = t1; c2 = t2;
  }
  if (threadIdx.x == 0) { dvec[0] = d0; dvec[1] = d1; dvec[2] = d2; }
}

// ---- k_finalize_p: partial conv3x3(s, WZ) over 16-ci quarter ----------------
// s = d0*v0 + d1*v1 + d2*v2 computed on-the-fly during staging (combine fused).
// grid 512 = b(2) | coQ(5) | ciQ(2); partials Fp[4]
__global__ __launch_bounds__(256) void k_finalize_p(const float* __restrict__ V,
                                                    const float* __restrict__ dvec,
                                                    const float* __restrict__ WZ,
                                                    float* __restrict__ Fp) {
  __shared__ __align__(16) float sS[3168];
  int tid = threadIdx.x, blk = blockIdx.x;
  int b = blk >> 7, coQ = (blk >> 2) & 31, ciQ = blk & 3;
  int wv = __builtin_amdgcn_readfirstlane(tid >> 6);
  int co = coQ * 4 + wv;                      // 0..127
  int strip4 = ((tid >> 3) & 7) * 4;
  int cg4 = (tid & 7) * 4;
  float d0 = dvec[0], d1 = dvec[1], d2 = dvec[2];
  for (int i = tid; i < 3168; i += 256) sS[i] = 0.f;
  int srow = tid >> 3, scg = tid & 7;
  size_t sb_off = (size_t)(b * 64 + ciQ * 16) * 1024 + srow * 32 + scg * 4;
  const float* v0b = V + sb_off;
  const float* v1b = V + VPLANE + sb_off;
  const float* v2b = V + 2 * VPLANE + sb_off;
  float* sd0 = sS + (srow + 2) * 44 + 2 + scg * 4;
  const float* wb_base = WZ + (size_t)co * 64 * 16;
  float wA[12], wB[12];
  float acc[16], dummy[16];
#pragma unroll
  for (int i = 0; i < 16; ++i) acc[i] = 0.f;
#define LOADS(off) ({ \
    float4 _a = *(const float4*)(v0b + (off)); \
    float4 _b = *(const float4*)(v1b + (off)); \
    float4 _c = *(const float4*)(v2b + (off)); \
    float4 _s; \
    _s.x = fmaf(d0, _a.x, fmaf(d1, _b.x, d2 * _c.x)); \
    _s.y = fmaf(d0, _a.y, fmaf(d1, _b.y, d2 * _c.y)); \
    _s.z = fmaf(d0, _a.z, fmaf(d1, _b.z, d2 * _c.z)); \
    _s.w = fmaf(d0, _a.w, fmaf(d1, _b.w, d2 * _c.w)); \
    _s; })
  float4 stg = LOADS(0);
  wload3(wb_base, ciQ * 16, wA);
  __syncthreads();
  stg_write(sd0, stg);
  __syncthreads();
  for (int ci = 0; ci < 16; ci += 2) {
    stg = LOADS((size_t)(ci + 1) * 1024);
    wload3(wb_base, ciQ * 16 + ci + 1, wB);
    conv16_3<false>(sS, wA, strip4, cg4, acc, dummy);
    stg_write(sd0 + 1584, stg);
    __syncthreads();
    bool more = (ci + 2 < 16);
    if (more) {
      stg = LOADS((size_t)(ci + 2) * 1024);
      wload3(wb_base, ciQ * 16 + ci + 2, wA);
    }
    conv16_3<false>(sS + 1584, wB, strip4, cg4, acc, dummy);
    if (more) stg_write(sd0, stg);
    __syncthreads();
  }
#undef LOADS
  size_t off = (size_t)ciQ * 524288 + (size_t)(b * 128 + co) * 1024 + strip4 * 32 + cg4;
#pragma unroll
  for (int k = 0; k < 4; ++k) {
    float4 o = {acc[k * 4], acc[k * 4 + 1], acc[k * 4 + 2], acc[k * 4 + 3]};
    *(float4*)(Fp + off + k * 32) = o;
  }
}

// ---- k_fsum: out = yp0 + Bp + sum Fp ----------------------------------------
// Bp lives in d_out; same-thread read-then-write.
__global__ __launch_bounds__(256) void k_fsum(const float* __restrict__ yp0,
                                              const float* __restrict__ Fp,
                                              float* __restrict__ out) {
  size_t i = (size_t)(blockIdx.x * 256 + threadIdx.x) * 4;
  float4 s = *(const float4*)(yp0 + i);
  float4 bp = *(const float4*)(out + i);
  s.x += bp.x; s.y += bp.y; s.z += bp.z; s.w += bp.w;
#pragma unroll
  for (int q = 0; q < 4; ++q) {
    float4 p = *(const float4*)(Fp + (size_t)q * 524288 + i);
    s.x += p.x; s.y += p.y; s.z += p.z; s.w += p.w;
  }
  *(float4*)(out + i) = s;
}

// ---- launch -----------------------------------------------------------------
extern "C" void kernel_launch(void* const* d_in, const int* in_sizes, int n_in,
                              void* d_out, int out_size, void* d_ws, size_t ws_size,
                              hipStream_t stream) {
  const float* x   = (const float*)d_in[0];
  const float* Wff = (const float*)d_in[1];
  const float* Wfb = (const float*)d_in[2];
  const float* Wb  = (const float*)d_in[3];
  float* out = (float*)d_out;

  float* yp0  = (float*)d_ws;                  // 524288
  float* V    = yp0 + 524288;                  // 3 * 262144
  float* G5   = V + (size_t)KRYLOV * VPLANE;   // 131072
  float* Gam  = G5 + 131072;                   // 16
  float* dvec = Gam + 16;                      // 16
  float* Pn   = dvec + 16;                     // 2 * 262144
  float* Pw   = Pn + (size_t)2 * 262144;       // 6 * 262144
  float* WI   = Pw + (size_t)6 * 262144;       // 131072
  float* WF   = WI + 131072;                   // 131072
  float* WZ   = WF + 131072;                   // 131072
  float* Q    = WZ + 131072;                   // 4 * 524288
  float* Bq   = Q + (size_t)4 * 524288;        // 4 * 524288
  float* Fp   = Bq + (size_t)4 * 524288;       // 4 * 524288
  float* Bp   = out;                           // bypass planes in d_out

  hipLaunchKernelGGL(k_prep,       dim3(96),  dim3(256), 0, stream, Wff, Wfb, Wb, WI, WF, WZ);
  hipLaunchKernelGGL(k_init_p,     dim3(512), dim3(256), 0, stream, x, WI, Q, Bq);
  hipLaunchKernelGGL(k_rsum,       dim3(512), dim3(256), 0, stream, Q, Bq, yp0, Bp);
  hipLaunchKernelGGL(k_gram,       dim3(64),  dim3(256), 0, stream, Wfb, G5, Gam);
  hipLaunchKernelGGL(k_forward_p,  dim3(512), dim3(256), 0, stream, yp0, WF, Pn, Pw);
  hipLaunchKernelGGL(k_vsub,       dim3(256), dim3(256), 0, stream, x, Pn, Pw, V);
  hipLaunchKernelGGL(k_applyGp,    dim3(512), dim3(256), 0, stream, V, Pn, Pw, G5);
  hipLaunchKernelGGL(k_sum8,       dim3(256), dim3(256), 0, stream, Pn, Pw, V + VPLANE);
  hipLaunchKernelGGL(k_applyGp,    dim3(512), dim3(256), 0, stream, V + VPLANE, Pn, Pw, G5);
  hipLaunchKernelGGL(k_sum8,       dim3(256), dim3(256), 0, stream, Pn, Pw, V + 2 * VPLANE);
  hipLaunchKernelGGL(k_gamma,      dim3(48),  dim3(256), 0, stream, V, Gam);
  hipLaunchKernelGGL(k_scalar,     dim3(1),   dim3(64),  0, stream, Gam, dvec);
  hipLaunchKernelGGL(k_finalize_p, dim3(512), dim3(256), 0, stream, V, dvec, WZ, Fp);
  hipLaunchKernelGGL(k_fsum,       dim3(512), dim3(256), 0, stream, yp0, Fp, out);
}

// Round 13
// 221.680 us; speedup vs baseline: 1.1256x; 1.0167x over previous
//
#include <hip/hip_runtime.h>

#define NUM_ITERS 500
#define LR_F 0.001f
#define KRYLOV 3
#define VPLANE 262144    // 4*64*1024 floats per Krylov vector
// 500 = 20 segments * 25 steps; C(25,1)=25, C(25,2)=300, C(25,3)=2300

// ---- register-safe unpack helpers -------------------------------------------
__device__ __forceinline__ void ldrow8b(const float* __restrict__ rp, float f[8]) {
  float4 a = *(const float4*)(rp);
  float4 b = *(const float4*)(rp + 4);
  f[0] = a.x; f[1] = a.y; f[2] = a.z; f[3] = a.w;
  f[4] = b.x; f[5] = b.y; f[6] = b.z; f[7] = b.w;
}

__device__ __forceinline__ void wload(const float* __restrict__ gb, int o, float w[28]) {
  const float4* g4 = (const float4*)(gb + o * 32);
#pragma unroll
  for (int i = 0; i < 7; ++i) {
    float4 v = g4[i];
    w[4 * i] = v.x; w[4 * i + 1] = v.y; w[4 * i + 2] = v.z; w[4 * i + 3] = v.w;
  }
}

__device__ __forceinline__ void wload3(const float* __restrict__ wb, int ci, float w[12]) {
  const float4* g4 = (const float4*)(wb + (size_t)ci * 16);
  float4 a = g4[0], b = g4[1], c = g4[2];
  w[0] = a.x; w[1] = a.y; w[2] = a.z; w[3] = a.w;
  w[4] = b.x; w[5] = b.y; w[6] = b.z; w[7] = b.w;
  w[8] = c.x; w[9] = c.y; w[10] = c.z; w[11] = c.w;
}

__device__ __forceinline__ void stg_write(float* sd, float4 v) {
  float2 u = {v.x, v.y}, w = {v.z, v.w};
  *(float2*)sd = u;
  *(float2*)(sd + 2) = w;
}

// ---- conv16_3: 3x3 pad1 over full-plane LDS (pitch 44, halo+2), 16 px -------
template <bool BYP>
__device__ __forceinline__ void conv16_3(const float* __restrict__ pb, const float w[12],
                                         int strip4, int cg4, float acc[16], float by[16]) {
  float wb = w[9];
#pragma unroll
  for (int r = 0; r < 6; ++r) {
    float f[8];
    ldrow8b(pb + (strip4 + 1 + r) * 44 + cg4, f);
#pragma unroll
    for (int k = 0; k < 4; ++k) {
      int di = r - k;
      if (di >= 0 && di < 3) {
#pragma unroll
        for (int dj = 0; dj < 3; ++dj) {
          float wv = w[di * 3 + dj];
#pragma unroll
          for (int c = 0; c < 4; ++c)
            acc[k * 4 + c] = fmaf(f[c + dj + 1], wv, acc[k * 4 + c]);
        }
        if (BYP && di == 1) {
#pragma unroll
          for (int c = 0; c < 4; ++c)
            by[k * 4 + c] = fmaf(f[c + 2], wb, by[k * 4 + c]);
        }
      }
    }
  }
}

// ---- conv16: 5x5 over full-plane LDS buffer (pitch 44, halo+2), 16 px -------
__device__ __forceinline__ void conv16(const float* __restrict__ pb, const float w[28],
                                       int strip4, int cg4, float acc[16]) {
#pragma unroll
  for (int r = 0; r < 8; ++r) {
    float f[8];
    ldrow8b(pb + (strip4 + r) * 44 + cg4, f);
#pragma unroll
    for (int k = 0; k < 4; ++k) {
      int di = r - k;
      if (di >= 0 && di < 5) {
#pragma unroll
        for (int dj = 0; dj < 5; ++dj) {
          float wv = w[di * 5 + dj];
#pragma unroll
          for (int c = 0; c < 4; ++c)
            acc[k * 4 + c] = fmaf(f[c + dj], wv, acc[k * 4 + c]);
        }
      }
    }
  }
}

// ---- k_prep_gram: weight tables (blocks 0..95) + 5x5 Gram (blocks 96..159) --
// WF[o(64)][c(128)][16] (forward, transposed); WI[co][ci][16] slot9=Wb;
// WZ[co][ci][16] (flipped). Gram: G[(o'*64+o)*32+tap], Gam zeroed.
__global__ __launch_bounds__(256) void k_prep_gram(const float* __restrict__ Wff,
                                                   const float* __restrict__ Wfb,
                                                   const float* __restrict__ Wb,
                                                   float* __restrict__ WI,
                                                   float* __restrict__ WF,
                                                   float* __restrict__ WZ,
                                                   float* __restrict__ G,
                                                   float* __restrict__ Gam) {
  __shared__ float wA[128 * 9];
  __shared__ float gred[256][25];
  int tid = threadIdx.x;
  if (blockIdx.x < 96) {
    int g = blockIdx.x * 256 + tid;
    int table = g >> 13, t = g & 8191;
    float w[16];
#pragma unroll
    for (int k = 0; k < 16; ++k) w[k] = 0.f;
    float* dst;
    if (table == 0) {
      int o = t >> 7, c = t & 127;
      const float* src = Wfb + (size_t)(c * 64 + o) * 9;
#pragma unroll
      for (int k = 0; k < 9; ++k) w[k] = src[k];
      dst = WF + (size_t)(o * 128 + c) * 16;
    } else if (table == 1) {
      const float* src = Wff + (size_t)t * 9;
#pragma unroll
      for (int k = 0; k < 9; ++k) w[k] = src[k];
      w[9] = Wb[t];
      dst = WI + (size_t)t * 16;
    } else {
      const float* src = Wfb + (size_t)t * 9;
#pragma unroll
      for (int k = 0; k < 9; ++k) w[k] = src[8 - k];
      dst = WZ + (size_t)t * 16;
    }
    float4 v0 = {w[0], w[1], w[2], w[3]};
    float4 v1 = {w[4], w[5], w[6], w[7]};
    float4 v2 = {w[8], w[9], w[10], w[11]};
    float4 v3 = {w[12], w[13], w[14], w[15]};
    ((float4*)dst)[0] = v0; ((float4*)dst)[1] = v1;
    ((float4*)dst)[2] = v2; ((float4*)dst)[3] = v3;
    return;
  }
  int op = blockIdx.x - 96;
  if (op == 0 && tid < 16) Gam[tid] = 0.f;
  for (int i = tid; i < 1152; i += 256) {
    int c = i / 9, k = i - c * 9;
    wA[i] = Wfb[(size_t)(c * 64 + op) * 9 + k];
  }
  __syncthreads();
  int o = tid & 63, part = tid >> 6;
  float g[25];
#pragma unroll
  for (int i = 0; i < 25; ++i) g[i] = 0.f;
  for (int c = part * 32; c < part * 32 + 32; ++c) {
    float b9[9];
#pragma unroll
    for (int k = 0; k < 9; ++k) b9[k] = Wfb[(size_t)(c * 64 + o) * 9 + k];
    const float* a9 = &wA[c * 9];
#pragma unroll
    for (int ei = 0; ei < 3; ++ei)
#pragma unroll
      for (int ej = 0; ej < 3; ++ej) {
        float av = a9[ei * 3 + ej];
#pragma unroll
        for (int di = 0; di < 3; ++di)
#pragma unroll
          for (int dj = 0; dj < 3; ++dj)
            g[(ei - di + 2) * 5 + (ej - dj + 2)] = fmaf(av, b9[di * 3 + dj],
                                                        g[(ei - di + 2) * 5 + (ej - dj + 2)]);
      }
  }
#pragma unroll
  for (int i = 0; i < 25; ++i) gred[tid][i] = g[i];
  __syncthreads();
  if (part == 0) {
    float* dst = G + ((size_t)op * 64 + o) * 32;
#pragma unroll
    for (int i = 0; i < 25; ++i)
      dst[i] = gred[tid][i] + gred[tid + 64][i] + gred[tid + 128][i] + gred[tid + 192][i];
#pragma unroll
    for (int i = 25; i < 32; ++i) dst[i] = 0.f;
  }
}

// ---- k_init_p: partial conv3x3(x,WI) + partial bypass over 16-ci quarter ----
// grid 512 = b(2) | ochQ(5) | ciQ(2); block: 4 och (wave-uniform) x 16 px/thr
__global__ __launch_bounds__(256) void k_init_p(const float* __restrict__ x,
                                                const float* __restrict__ WI,
                                                float* __restrict__ Q,
                                                float* __restrict__ Bq) {
  __shared__ __align__(16) float sS[3168];    // 2 x 36*44
  int tid = threadIdx.x, blk = blockIdx.x;
  int b = blk >> 7, ochQ = (blk >> 2) & 31, ciQ = blk & 3;
  int wv = __builtin_amdgcn_readfirstlane(tid >> 6);
  int och = ochQ * 4 + wv;                    // 0..127
  int strip4 = ((tid >> 3) & 7) * 4;
  int cg4 = (tid & 7) * 4;
  for (int i = tid; i < 3168; i += 256) sS[i] = 0.f;
  int srow = tid >> 3, scg = tid & 7;
  const float* sbase = x + (size_t)(b * 64 + ciQ * 16) * 1024 + srow * 32 + scg * 4;
  float* sd0 = sS + (srow + 2) * 44 + 2 + scg * 4;
  const float* wb_base = WI + (size_t)och * 64 * 16;
  float wA[12], wB[12];
  float acc[16], by[16];
#pragma unroll
  for (int i = 0; i < 16; ++i) { acc[i] = 0.f; by[i] = 0.f; }
  float4 stg = *(const float4*)(sbase);
  wload3(wb_base, ciQ * 16, wA);
  __syncthreads();
  stg_write(sd0, stg);
  __syncthreads();
  for (int ci = 0; ci < 16; ci += 2) {
    stg = *(const float4*)(sbase + (size_t)(ci + 1) * 1024);
    wload3(wb_base, ciQ * 16 + ci + 1, wB);
    conv16_3<true>(sS, wA, strip4, cg4, acc, by);
    stg_write(sd0 + 1584, stg);
    __syncthreads();
    bool more = (ci + 2 < 16);
    if (more) {
      stg = *(const float4*)(sbase + (size_t)(ci + 2) * 1024);
      wload3(wb_base, ciQ * 16 + ci + 2, wA);
    }
    conv16_3<true>(sS + 1584, wB, strip4, cg4, acc, by);
    if (more) stg_write(sd0, stg);
    __syncthreads();
  }
  size_t off = (size_t)ciQ * 524288 + (size_t)(b * 128 + och) * 1024 + strip4 * 32 + cg4;
#pragma unroll
  for (int k = 0; k < 4; ++k) {
    float4 o = {acc[k * 4], acc[k * 4 + 1], acc[k * 4 + 2], acc[k * 4 + 3]};
    float4 bo = {by[k * 4], by[k * 4 + 1], by[k * 4 + 2], by[k * 4 + 3]};
    *(float4*)(Q + off + k * 32) = o;
    *(float4*)(Bq + off + k * 32) = bo;
  }
}

// ---- k_forward_p: partial conv3x3(relu(sum Q), WF) over 16-ci octant --------
// rsum fused into staging: yp0 never materialized. grid 512 = b|ochQ(16)|ciO(8)
__global__ __launch_bounds__(256) void k_forward_p(const float* __restrict__ Q,
                                                   const float* __restrict__ WF,
                                                   float* __restrict__ PA) {
  __shared__ __align__(16) float sS[3168];
  int tid = threadIdx.x, blk = blockIdx.x;
  int b = blk >> 7, ochQ = (blk >> 3) & 15, ciO = blk & 7;
  int wv = __builtin_amdgcn_readfirstlane(tid >> 6);
  int och = ochQ * 4 + wv;                    // 0..63
  int strip4 = ((tid >> 3) & 7) * 4;
  int cg4 = (tid & 7) * 4;
  for (int i = tid; i < 3168; i += 256) sS[i] = 0.f;
  int srow = tid >> 3, scg = tid & 7;
  size_t qbase = (size_t)(b * 128 + ciO * 16) * 1024 + srow * 32 + scg * 4;
  float* sd0 = sS + (srow + 2) * 44 + 2 + scg * 4;
  const float* wb_base = WF + (size_t)och * 128 * 16;
  float wA[12], wB[12];
  float acc[16], dummy[16];
#pragma unroll
  for (int i = 0; i < 16; ++i) acc[i] = 0.f;
#define LDQ(ci) ({ size_t _a = qbase + (size_t)(ci) * 1024; \
    float4 _q0 = *(const float4*)(Q + _a); \
    float4 _q1 = *(const float4*)(Q + 524288 + _a); \
    float4 _q2 = *(const float4*)(Q + 2 * 524288 + _a); \
    float4 _q3 = *(const float4*)(Q + 3 * 524288 + _a); \
    float4 _s; \
    _s.x = _q0.x + _q1.x + _q2.x + _q3.x; \
    _s.y = _q0.y + _q1.y + _q2.y + _q3.y; \
    _s.z = _q0.z + _q1.z + _q2.z + _q3.z; \
    _s.w = _q0.w + _q1.w + _q2.w + _q3.w; \
    _s.x = _s.x > 0.f ? _s.x : 0.f; _s.y = _s.y > 0.f ? _s.y : 0.f; \
    _s.z = _s.z > 0.f ? _s.z : 0.f; _s.w = _s.w > 0.f ? _s.w : 0.f; \
    _s; })
  float4 stg = LDQ(0);
  wload3(wb_base, ciO * 16, wA);
  __syncthreads();
  stg_write(sd0, stg);
  __syncthreads();
  for (int ci = 0; ci < 16; ci += 2) {
    stg = LDQ(ci + 1);
    wload3(wb_base, ciO * 16 + ci + 1, wB);
    conv16_3<false>(sS, wA, strip4, cg4, acc, dummy);
    stg_write(sd0 + 1584, stg);
    __syncthreads();
    bool more = (ci + 2 < 16);
    if (more) {
      stg = LDQ(ci + 2);
      wload3(wb_base, ciO * 16 + ci + 2, wA);
    }
    conv16_3<false>(sS + 1584, wB, strip4, cg4, acc, dummy);
    if (more) stg_write(sd0, stg);
    __syncthreads();
  }
#undef LDQ
  float* dst = PA + (size_t)ciO * 262144 + (size_t)(b * 64 + och) * 1024 + strip4 * 32 + cg4;
#pragma unroll
  for (int k = 0; k < 4; ++k) {
    float4 o = {acc[k * 4], acc[k * 4 + 1], acc[k * 4 + 2], acc[k * 4 + 3]};
    *(float4*)(dst + k * 32) = o;
  }
}

// ---- k_applyGp<MODE>: partial G(*)v over 8-ci octant ------------------------
// MODE 1: v = x - sum(Pin) computed in staging (vsub fused); MODE 2: v = sum(Pin)
// (sum8 fused). ochQ==0 blocks also write the staged v to Vout (for gamma etc).
// grid 512 = b(2) | ochQ(4) | ciO(3).
template <int MODE>
__global__ __launch_bounds__(256) void k_applyGp(const float* __restrict__ xin,
                                                 const float* __restrict__ Pin,
                                                 float* __restrict__ Pout,
                                                 const float* __restrict__ G,
                                                 float* __restrict__ Vout) {
  __shared__ __align__(16) float sS[3168];    // 2 x 36*44
  int tid = threadIdx.x, blk = blockIdx.x;
  int b = blk >> 7, ochQ = (blk >> 3) & 15, ciO = blk & 7;
  bool wv0 = (ochQ == 0);
  int wv = __builtin_amdgcn_readfirstlane(tid >> 6);
  int och = ochQ * 4 + wv;
  int strip4 = ((tid >> 3) & 7) * 4;
  int cg4 = (tid & 7) * 4;
  for (int i = tid; i < 3168; i += 256) sS[i] = 0.f;
  int srow = tid >> 3, scg = tid & 7;
  size_t vbase = (size_t)(b * 64 + ciO * 8) * 1024 + srow * 32 + scg * 4;
  float* sd0 = sS + (srow + 2) * 44 + 2 + scg * 4;
  const float* gb = G + (size_t)och * 2048;
  float wA[28], wB[28];
  float acc[16];
#pragma unroll
  for (int i = 0; i < 16; ++i) acc[i] = 0.f;
#define LDV(ci) ({ size_t _a = vbase + (size_t)(ci) * 1024; \
    float4 _s = {0.f, 0.f, 0.f, 0.f}; \
    _Pragma("unroll") \
    for (int _o = 0; _o < 8; ++_o) { \
      float4 _p = *(const float4*)(Pin + (size_t)_o * 262144 + _a); \
      _s.x += _p.x; _s.y += _p.y; _s.z += _p.z; _s.w += _p.w; \
    } \
    if (MODE == 1) { \
      float4 _x = *(const float4*)(xin + _a); \
      _s.x = _x.x - _s.x; _s.y = _x.y - _s.y; \
      _s.z = _x.z - _s.z; _s.w = _x.w - _s.w; \
    } \
    _s; })
  float4 stg = LDV(0);
  wload(gb, ciO * 8, wA);
  __syncthreads();
  stg_write(sd0, stg);
  if (wv0) *(float4*)(Vout + vbase) = stg;
  __syncthreads();
  for (int ci = 0; ci < 8; ci += 2) {
    stg = LDV(ci + 1);
    wload(gb, ciO * 8 + ci + 1, wB);
    conv16(sS, wA, strip4, cg4, acc);
    stg_write(sd0 + 1584, stg);
    if (wv0) *(float4*)(Vout + vbase + (size_t)(ci + 1) * 1024) = stg;
    __syncthreads();
    bool more = (ci + 2 < 8);
    if (more) {
      stg = LDV(ci + 2);
      wload(gb, ciO * 8 + ci + 2, wA);
    }
    conv16(sS + 1584, wB, strip4, cg4, acc);
    if (more) {
      stg_write(sd0, stg);
      if (wv0) *(float4*)(Vout + vbase + (size_t)(ci + 2) * 1024) = stg;
    }
    __syncthreads();
  }
#undef LDV
  float* dst = Pout + (size_t)ciO * 262144 + (size_t)(b * 64 + och) * 1024 + strip4 * 32 + cg4;
#pragma unroll
  for (int k = 0; k < 4; ++k) {
    float4 o = {acc[k * 4], acc[k * 4 + 1], acc[k * 4 + 2], acc[k * 4 + 3]};
    *(float4*)(dst + k * 32) = o;
  }
}

// ---- k_sum8: vout = sum of 8 contiguous partials ----------------------------
__global__ __launch_bounds__(256) void k_sum8(const float* __restrict__ P,
                                              float* __restrict__ vout) {
  size_t i = (size_t)(blockIdx.x * 256 + threadIdx.x) * 4;
  float4 s = {0.f, 0.f, 0.f, 0.f};
#pragma unroll
  for (int o = 0; o < 8; ++o) {
    float4 q = *(const float4*)(P + (size_t)o * 262144 + i);
    s.x += q.x; s.y += q.y; s.z += q.z; s.w += q.w;
  }
  *(float4*)(vout + i) = s;
}

// ---- k_gamma ----------------------------------------------------------------
__global__ __launch_bounds__(256) void k_gamma(const float* __restrict__ V,
                                               float* __restrict__ Gam) {
  __shared__ float ws4[4];
  int tid = threadIdx.x;
  int p = blockIdx.x >> 3, slice = blockIdx.x & 7;
  int i = 0, rem = p;
  while (rem >= KRYLOV - i) { rem -= KRYLOV - i; ++i; }
  int j = i + rem;
  const float4* vi = (const float4*)(V + (size_t)i * VPLANE);
  const float4* vj = (const float4*)(V + (size_t)j * VPLANE);
  int base = slice * 8192;
  float acc = 0.f;
  for (int t = tid; t < 8192; t += 256) {
    float4 a = vi[base + t], c = vj[base + t];
    acc = fmaf(a.x, c.x, acc);
    acc = fmaf(a.y, c.y, acc);
    acc = fmaf(a.z, c.z, acc);
    acc = fmaf(a.w, c.w, acc);
  }
#pragma unroll
  for (int d = 32; d; d >>= 1) acc += __shfl_down(acc, d, 64);
  if ((tid & 63) == 0) ws4[tid >> 6] = acc;
  __syncthreads();
  if (tid == 0) {
    float tot = ws4[0] + ws4[1] + ws4[2] + ws4[3];
    atomicAdd(&Gam[i * KRYLOV + j], tot);
    if (i != j) atomicAdd(&Gam[j * KRYLOV + i], tot);
  }
}

// ---- k_finalize_p: partial conv3x3(s, WZ); scalar recurrence inlined --------
// s = d0*v0+d1*v1+d2*v2 computed in staging. grid 512 = b(2)|coQ(5)|ciQ(2).
__global__ __launch_bounds__(256) void k_finalize_p(const float* __restrict__ V,
                                                    const float* __restrict__ Gam,
                                                    const float* __restrict__ WZ,
                                                    float* __restrict__ Fp) {
  __shared__ __align__(16) float sS[3168];
  int tid = threadIdx.x, blk = blockIdx.x;
  int b = blk >> 7, coQ = (blk >> 2) & 31, ciQ = blk & 3;
  int wv = __builtin_amdgcn_readfirstlane(tid >> 6);
  int co = coQ * 4 + wv;                      // 0..127
  int strip4 = ((tid >> 3) & 7) * 4;
  int cg4 = (tid & 7) * 4;
  // inline 20-segment closed-form recurrence (was k_scalar)
  float g00 = Gam[0], g01 = Gam[1], g02 = Gam[2];
  float g11 = Gam[4], g12 = Gam[5], g22 = Gam[8];
  float c0 = 1.f, c1 = 0.f, c2 = 0.f;
  float d0 = 0.f, d1 = 0.f, d2 = 0.f;
#pragma unroll
  for (int seg = 0; seg < 20; ++seg) {
    float pr = g00 * c0 * c0 + g11 * c1 * c1 + g22 * c2 * c2 +
               2.f * (g01 * c0 * c1 + g02 * c0 * c2 + g12 * c1 * c2);
    float a = LR_F * __builtin_amdgcn_rsqf(pr);
    float a2 = a * a, a3 = a2 * a;
    d0 += 25.f * a * c0;
    d1 += 25.f * a * c1 - 300.f * a2 * c0;
    d2 += 25.f * a * c2 - 300.f * a2 * c1 + 2300.f * a3 * c0;
    float t1 = c1 - 25.f * a * c0;
    float t2 = c2 - 25.f * a * c1 + 300.f * a2 * c0;
    c1 = t1; c2 = t2;
  }
  for (int i = tid; i < 3168; i += 256) sS[i] = 0.f;
  int srow = tid >> 3, scg = tid & 7;
  size_t sb_off = (size_t)(b * 64 + ciQ * 16) * 1024 + srow * 32 + scg * 4;
  const float* v0b = V + sb_off;
  const float* v1b = V + VPLANE + sb_off;
  const float* v2b = V + 2 * VPLANE + sb_off;
  float* sd0 = sS + (srow + 2) * 44 + 2 + scg * 4;
  const float* wb_base = WZ + (size_t)co * 64 * 16;
  float wA[12], wB[12];
  float acc[16], dummy[16];
#pragma unroll
  for (int i = 0; i < 16; ++i) acc[i] = 0.f;
#define LOADS(off) ({ \
    float4 _a = *(const float4*)(v0b + (off)); \
    float4 _b = *(const float4*)(v1b + (off)); \
    float4 _c = *(const float4*)(v2b + (off)); \
    float4 _s; \
    _s.x = fmaf(d0, _a.x, fmaf(d1, _b.x, d2 * _c.x)); \
    _s.y = fmaf(d0, _a.y, fmaf(d1, _b.y, d2 * _c.y)); \
    _s.z = fmaf(d0, _a.z, fmaf(d1, _b.z, d2 * _c.z)); \
    _s.w = fmaf(d0, _a.w, fmaf(d1, _b.w, d2 * _c.w)); \
    _s; })
  float4 stg = LOADS(0);
  wload3(wb_base, ciQ * 16, wA);
  __syncthreads();
  stg_write(sd0, stg);
  __syncthreads();
  for (int ci = 0; ci < 16; ci += 2) {
    stg = LOADS((size_t)(ci + 1) * 1024);
    wload3(wb_base, ciQ * 16 + ci + 1, wB);
    conv16_3<false>(sS, wA, strip4, cg4, acc, dummy);
    stg_write(sd0 + 1584, stg);
    __syncthreads();
    bool more = (ci + 2 < 16);
    if (more) {
      stg = LOADS((size_t)(ci + 2) * 1024);
      wload3(wb_base, ciQ * 16 + ci + 2, wA);
    }
    conv16_3<false>(sS + 1584, wB, strip4, cg4, acc, dummy);
    if (more) stg_write(sd0, stg);
    __syncthreads();
  }
#undef LOADS
  size_t off = (size_t)ciQ * 524288 + (size_t)(b * 128 + co) * 1024 + strip4 * 32 + cg4;
#pragma unroll
  for (int k = 0; k < 4; ++k) {
    float4 o = {acc[k * 4], acc[k * 4 + 1], acc[k * 4 + 2], acc[k * 4 + 3]};
    *(float4*)(Fp + off + k * 32) = o;
  }
}

// ---- k_fsum: out = relu(sum Q) + sum Bq + sum Fp ----------------------------
__global__ __launch_bounds__(256) void k_fsum(const float* __restrict__ Q,
                                              const float* __restrict__ Bq,
                                              const float* __restrict__ Fp,
                                              float* __restrict__ out) {
  size_t i = (size_t)(blockIdx.x * 256 + threadIdx.x) * 4;
  float4 s = {0.f, 0.f, 0.f, 0.f}, t = {0.f, 0.f, 0.f, 0.f};
#pragma unroll
  for (int q = 0; q < 4; ++q) {
    float4 a = *(const float4*)(Q + (size_t)q * 524288 + i);
    float4 b = *(const float4*)(Bq + (size_t)q * 524288 + i);
    s.x += a.x; s.y += a.y; s.z += a.z; s.w += a.w;
    t.x += b.x; t.y += b.y; t.z += b.z; t.w += b.w;
  }
  s.x = (s.x > 0.f ? s.x : 0.f) + t.x;
  s.y = (s.y > 0.f ? s.y : 0.f) + t.y;
  s.z = (s.z > 0.f ? s.z : 0.f) + t.z;
  s.w = (s.w > 0.f ? s.w : 0.f) + t.w;
#pragma unroll
  for (int q = 0; q < 4; ++q) {
    float4 p = *(const float4*)(Fp + (size_t)q * 524288 + i);
    s.x += p.x; s.y += p.y; s.z += p.z; s.w += p.w;
  }
  *(float4*)(out + i) = s;
}

// ---- launch -----------------------------------------------------------------
extern "C" void kernel_launch(void* const* d_in, const int* in_sizes, int n_in,
                              void* d_out, int out_size, void* d_ws, size_t ws_size,
                              hipStream_t stream) {
  const float* x   = (const float*)d_in[0];
  const float* Wff = (const float*)d_in[1];
  const float* Wfb = (const float*)d_in[2];
  const float* Wb  = (const float*)d_in[3];
  float* out = (float*)d_out;

  float* V    = (float*)d_ws;                  // 3 * 262144
  float* G5   = V + (size_t)KRYLOV * VPLANE;   // 131072
  float* Gam  = G5 + 131072;                   // 16
  float* PA   = Gam + 16;                      // 8 * 262144
  float* PB   = PA + (size_t)8 * 262144;       // 8 * 262144
  float* WI   = PB + (size_t)8 * 262144;       // 131072
  float* WF   = WI + 131072;                   // 131072
  float* WZ   = WF + 131072;                   // 131072
  float* Q    = WZ + 131072;                   // 4 * 524288
  float* Bq   = Q + (size_t)4 * 524288;        // 4 * 524288
  float* Fp   = Bq + (size_t)4 * 524288;       // 4 * 524288

  hipLaunchKernelGGL(k_prep_gram,   dim3(160), dim3(256), 0, stream,
                     Wff, Wfb, Wb, WI, WF, WZ, G5, Gam);
  hipLaunchKernelGGL(k_init_p,      dim3(512), dim3(256), 0, stream, x, WI, Q, Bq);
  hipLaunchKernelGGL(k_forward_p,   dim3(512), dim3(256), 0, stream, Q, WF, PA);
  hipLaunchKernelGGL((k_applyGp<1>), dim3(512), dim3(256), 0, stream,
                     x, PA, PB, G5, V);
  hipLaunchKernelGGL((k_applyGp<2>), dim3(512), dim3(256), 0, stream,
                     x, PB, PA, G5, V + VPLANE);
  hipLaunchKernelGGL(k_sum8,        dim3(256), dim3(256), 0, stream, PA, V + 2 * VPLANE);
  hipLaunchKernelGGL(k_gamma,       dim3(48),  dim3(256), 0, stream, V, Gam);
  hipLaunchKernelGGL(k_finalize_p,  dim3(512), dim3(256), 0, stream, V, Gam, WZ, Fp);
  hipLaunchKernelGGL(k_fsum,        dim3(512), dim3(256), 0, stream, Q, Bq, Fp, out);
}